// Round 3
// baseline (899.082 us; speedup 1.0000x reference)
//
#include <hip/hip_runtime.h>
#include <hip/hip_bf16.h>

#define EPS 1e-5f
#define BKSH 6   // bucket = dst >> BKSH

// ---------------------------------------------------------------- zero ints
__global__ __launch_bounds__(256) void k_zero(int* p, int n) {
    int i = blockIdx.x * 256 + threadIdx.x;
    if (i < n) p[i] = 0;
}

// ---------------------------------------------------------------- histogram
__global__ __launch_bounds__(256) void k_hist(const int* __restrict__ dst,
                                              int* __restrict__ counts, int nE) {
    int i = blockIdx.x * 256 + threadIdx.x;
    if (i < nE) atomicAdd(&counts[dst[i]], 1);
}

// ---------------------------------------------------------------- scan (3 phases)
__global__ __launch_bounds__(256) void k_scan1(const int* __restrict__ counts,
                                               int* __restrict__ bsums, int n) {
    __shared__ int sdata[256];
    int base = blockIdx.x * 2048;
    int t = threadIdx.x;
    int s = 0;
#pragma unroll
    for (int i = 0; i < 8; ++i) {
        int idx = base + t * 8 + i;
        if (idx < n) s += counts[idx];
    }
    sdata[t] = s;
    __syncthreads();
    for (int off = 128; off > 0; off >>= 1) {
        if (t < off) sdata[t] += sdata[t + off];
        __syncthreads();
    }
    if (t == 0) bsums[blockIdx.x] = sdata[0];
}

__global__ __launch_bounds__(64) void k_scan2(int* __restrict__ bsums, int nb) {
    if (threadIdx.x == 0 && blockIdx.x == 0) {
        int acc = 0;
        for (int i = 0; i < nb; ++i) { int v = bsums[i]; bsums[i] = acc; acc += v; }
    }
}

__global__ __launch_bounds__(256) void k_scan3(const int* __restrict__ counts,
                                               const int* __restrict__ bsums,
                                               int* __restrict__ rowstart,
                                               int n, int nE) {
    __shared__ int sth[256];
    int base = blockIdx.x * 2048;
    int t = threadIdx.x;
    int loc[8];
    int s = 0;
#pragma unroll
    for (int i = 0; i < 8; ++i) {
        int idx = base + t * 8 + i;
        loc[i] = s;
        s += (idx < n) ? counts[idx] : 0;
    }
    sth[t] = s;
    __syncthreads();
    for (int off = 1; off < 256; off <<= 1) {
        int tmp = (t >= off) ? sth[t - off] : 0;
        __syncthreads();
        sth[t] += tmp;
        __syncthreads();
    }
    int excl = sth[t] - s + bsums[blockIdx.x];
#pragma unroll
    for (int i = 0; i < 8; ++i) {
        int idx = base + t * 8 + i;
        if (idx < n) rowstart[idx] = excl + loc[i];
    }
    if (blockIdx.x == 0 && t == 0) rowstart[n] = nE;
}

// ---------------------------------------------------------------- bucket cursors
__global__ __launch_bounds__(256) void k_binit(const int* __restrict__ rowstart,
                                               int* __restrict__ bcursor, int nbk) {
    int bk = blockIdx.x * 256 + threadIdx.x;
    if (bk < nbk) bcursor[bk] = rowstart[bk << BKSH];
}

// ---------------------------------------------------------------- partition
// scatter edges into dst-bucket-grouped tmp; ~1563 sequential cursors ->
// dirty-line working set ~100 KB (L2-resident, lines fill before eviction)
__global__ __launch_bounds__(256) void k_part(const int* __restrict__ srci,
                                              const int* __restrict__ dsti,
                                              int* __restrict__ bcursor,
                                              unsigned long long* __restrict__ tmp,
                                              int nE) {
    int e = blockIdx.x * 256 + threadIdx.x;
    if (e < nE) {
        int s = srci[e], d = dsti[e];
        int p = atomicAdd(&bcursor[d >> BKSH], 1);
        tmp[p] = ((unsigned long long)(unsigned)d << 32) | (unsigned)s;
    }
}

// ---------------------------------------------------------------- CSR fill
// linear read of bucket-grouped tmp; cursor atomics + col writes confined to
// each bucket's ~16 KB window -> L2-hot, no line thrash
__global__ __launch_bounds__(256) void k_fill2(const unsigned long long* __restrict__ tmp,
                                               int* __restrict__ cursor,
                                               int* __restrict__ col, int nE) {
    int e = blockIdx.x * 256 + threadIdx.x;
    if (e < nE) {
        unsigned long long v = tmp[e];
        int d = (int)(v >> 32);
        int s = (int)(v & 0xffffffffu);
        int q = atomicAdd(&cursor[d], 1);
        col[q] = s;
    }
}

// ---------------------------------------------------------------- linear
__global__ __launch_bounds__(256) void k_linear(const float* __restrict__ X,
                                                const float* __restrict__ W,
                                                const float* __restrict__ bias,
                                                float* __restrict__ out,
                                                int nRows) {
    __shared__ float xs[64][132];
    int row0 = blockIdx.x * 64;
    int tid = threadIdx.x;
    for (int i = tid; i < 64 * 32; i += 256) {
        int r = i >> 5, c4 = (i & 31) << 2;
        float4 v = make_float4(0.f, 0.f, 0.f, 0.f);
        int row = row0 + r;
        if (row < nRows) v = *(const float4*)(X + (size_t)row * 128 + c4);
        *(float4*)&xs[r][c4] = v;
    }
    __syncthreads();

    int cg = tid & 15, rg = tid >> 4;
    int c0 = cg * 8, r0 = rg * 4;
    float acc[4][8];
    float4 b0 = *(const float4*)(bias + c0);
    float4 b1 = *(const float4*)(bias + c0 + 4);
#pragma unroll
    for (int r = 0; r < 4; ++r) {
        acc[r][0] = b0.x; acc[r][1] = b0.y; acc[r][2] = b0.z; acc[r][3] = b0.w;
        acc[r][4] = b1.x; acc[r][5] = b1.y; acc[r][6] = b1.z; acc[r][7] = b1.w;
    }

    for (int k0 = 0; k0 < 128; k0 += 4) {
        float4 xv[4];
#pragma unroll
        for (int r = 0; r < 4; ++r) xv[r] = *(const float4*)&xs[r0 + r][k0];
#pragma unroll
        for (int kk = 0; kk < 4; ++kk) {
            int k = k0 + kk;
            float4 w0 = *(const float4*)(W + k * 128 + c0);
            float4 w1 = *(const float4*)(W + k * 128 + c0 + 4);
            float wv[8] = {w0.x, w0.y, w0.z, w0.w, w1.x, w1.y, w1.z, w1.w};
#pragma unroll
            for (int r = 0; r < 4; ++r) {
                float xk = (&xv[r].x)[kk];
#pragma unroll
                for (int j = 0; j < 8; ++j) acc[r][j] = fmaf(xk, wv[j], acc[r][j]);
            }
        }
    }

#pragma unroll
    for (int r = 0; r < 4; ++r) {
        int row = row0 + r0 + r;
        if (row >= nRows) continue;
        *(float4*)(out + (size_t)row * 128 + c0) =
            make_float4(acc[r][0], acc[r][1], acc[r][2], acc[r][3]);
        *(float4*)(out + (size_t)row * 128 + c0 + 4) =
            make_float4(acc[r][4], acc[r][5], acc[r][6], acc[r][7]);
    }
}

// ---------------------------------------------------------------- gather
template <bool FUSE_BN>
__global__ __launch_bounds__(256) void k_gather(const float* __restrict__ src,
                                                const int* __restrict__ rowstart,
                                                const int* __restrict__ col,
                                                const float* __restrict__ g,
                                                const float* __restrict__ be,
                                                const float* __restrict__ m,
                                                const float* __restrict__ v,
                                                float* __restrict__ out, int nRows) {
    int r = blockIdx.x * 4 + (threadIdx.x >> 6);
    if (r >= nRows) return;
    int lane = threadIdx.x & 63;
    int d0 = lane * 2;
    int s = rowstart[r], e = rowstart[r + 1];

    float2 acc = *(const float2*)(src + (size_t)r * 128 + d0);   // self loop
    int j = s;
    for (; j + 8 <= e; j += 8) {
        int ci[8];
#pragma unroll
        for (int u = 0; u < 8; ++u) ci[u] = col[j + u];
        float2 t[8];
#pragma unroll
        for (int u = 0; u < 8; ++u)
            t[u] = *(const float2*)(src + (size_t)ci[u] * 128 + d0);
#pragma unroll
        for (int u = 0; u < 8; ++u) { acc.x += t[u].x; acc.y += t[u].y; }
    }
    for (; j < e; ++j) {
        int ci = col[j];
        float2 a = *(const float2*)(src + (size_t)ci * 128 + d0);
        acc.x += a.x;
        acc.y += a.y;
    }
    float rc = 1.0f / (float)(e - s + 1);
    float2 o;
    if (FUSE_BN) {
        float2 gv = *(const float2*)(g + d0);
        float2 bev = *(const float2*)(be + d0);
        float2 mv = *(const float2*)(m + d0);
        float2 vv = *(const float2*)(v + d0);
        o.x = fmaxf((acc.x * rc - mv.x) * rsqrtf(vv.x + EPS) * gv.x + bev.x, 0.f);
        o.y = fmaxf((acc.y * rc - mv.y) * rsqrtf(vv.y + EPS) * gv.y + bev.y, 0.f);
    } else {
        o.x = acc.x * rc;
        o.y = acc.y * rc;
    }
    *(float2*)(out + (size_t)r * 128 + d0) = o;
}

// ---------------------------------------------------------------- final head
__global__ __launch_bounds__(256) void k_final(const float* __restrict__ xin,
                                               const float* __restrict__ Wc1,
                                               const float* __restrict__ bc1,
                                               const float* __restrict__ Wc2,
                                               const float* __restrict__ bc2,
                                               float* __restrict__ out, int nRows) {
    __shared__ float xs[32][132];
    __shared__ float w1s[128][64];
    __shared__ float hs[32][68];
    int row0 = blockIdx.x * 32;
    int tid = threadIdx.x;

    for (int i = tid; i < 2048; i += 256) {
        int kk = i >> 4, c4 = (i & 15) << 2;
        *(float4*)&w1s[kk][c4] = *(const float4*)(Wc1 + kk * 64 + c4);
    }
    for (int i = tid; i < 1024; i += 256) {
        int r = i >> 5, c4 = (i & 31) << 2;
        int row = row0 + r;
        float4 o = make_float4(0.f, 0.f, 0.f, 0.f);
        if (row < nRows) o = *(const float4*)(xin + (size_t)row * 128 + c4);
        *(float4*)&xs[r][c4] = o;
    }
    __syncthreads();

    int cg = tid & 15, rg = tid >> 4;
    int c0 = cg * 4, r0 = rg * 2;
    float acc[2][4];
    float4 bc = *(const float4*)(bc1 + c0);
    acc[0][0] = bc.x; acc[0][1] = bc.y; acc[0][2] = bc.z; acc[0][3] = bc.w;
    acc[1][0] = bc.x; acc[1][1] = bc.y; acc[1][2] = bc.z; acc[1][3] = bc.w;
    for (int k = 0; k < 128; ++k) {
        float4 w4 = *(const float4*)&w1s[k][c0];
        float x0 = xs[r0][k], x1 = xs[r0 + 1][k];
        acc[0][0] = fmaf(x0, w4.x, acc[0][0]);
        acc[0][1] = fmaf(x0, w4.y, acc[0][1]);
        acc[0][2] = fmaf(x0, w4.z, acc[0][2]);
        acc[0][3] = fmaf(x0, w4.w, acc[0][3]);
        acc[1][0] = fmaf(x1, w4.x, acc[1][0]);
        acc[1][1] = fmaf(x1, w4.y, acc[1][1]);
        acc[1][2] = fmaf(x1, w4.z, acc[1][2]);
        acc[1][3] = fmaf(x1, w4.w, acc[1][3]);
    }
    *(float4*)&hs[r0][c0] = make_float4(fmaxf(acc[0][0], 0.f), fmaxf(acc[0][1], 0.f),
                                        fmaxf(acc[0][2], 0.f), fmaxf(acc[0][3], 0.f));
    *(float4*)&hs[r0 + 1][c0] = make_float4(fmaxf(acc[1][0], 0.f), fmaxf(acc[1][1], 0.f),
                                            fmaxf(acc[1][2], 0.f), fmaxf(acc[1][3], 0.f));
    __syncthreads();

    if (tid < 64) {
        int r = tid >> 1, oc = tid & 1;
        float s = bc2[oc];
        for (int c = 0; c < 64; ++c) s = fmaf(hs[r][c], Wc2[c * 2 + oc], s);
        int row = row0 + r;
        if (row < nRows) out[(size_t)row * 2 + oc] = s;
    }
}

// ---------------------------------------------------------------- launch
extern "C" void kernel_launch(void* const* d_in, const int* in_sizes, int n_in,
                              void* d_out, int out_size, void* d_ws, size_t ws_size,
                              hipStream_t stream) {
    const float* x   = (const float*)d_in[0];
    const int*   ei  = (const int*)d_in[1];
    const float* W1  = (const float*)d_in[2];
    const float* b1  = (const float*)d_in[3];
    const float* g1  = (const float*)d_in[4];
    const float* be1 = (const float*)d_in[5];
    const float* m1  = (const float*)d_in[6];
    const float* v1  = (const float*)d_in[7];
    const float* W2  = (const float*)d_in[8];
    const float* b2  = (const float*)d_in[9];
    const float* g2  = (const float*)d_in[10];
    const float* be2 = (const float*)d_in[11];
    const float* m2  = (const float*)d_in[12];
    const float* v2  = (const float*)d_in[13];
    const float* Wc1 = (const float*)d_in[14];
    const float* bc1 = (const float*)d_in[15];
    const float* Wc2 = (const float*)d_in[16];
    const float* bc2 = (const float*)d_in[17];

    const int N_ = in_sizes[0] / 128;
    const int E_ = in_sizes[1] / 2;
    const int* srci = ei;
    const int* dsti = ei + E_;
    const int NBK = (N_ + 63) >> BKSH;

    float* A = (float*)d_ws;                       // [N,128]
    float* B = A + (size_t)N_ * 128;               // [N,128]; tmp aliases B
    unsigned long long* tmp = (unsigned long long*)B;   // [E] u64, dead before gather1
    int* counts   = (int*)(B + (size_t)N_ * 128);  // N (reused as cursor)
    int* rowstart = counts + N_;                   // N+1
    int* bsums    = rowstart + N_ + 1;             // 256
    int* bcursor  = bsums + 256;                   // 2048
    int* col      = bcursor + 2048;                // E

    const int nb = (N_ + 2047) / 2048;

    // ---- CSR build
    k_zero <<<(N_ + 255) / 256, 256, 0, stream>>>(counts, N_);
    k_hist <<<(E_ + 255) / 256, 256, 0, stream>>>(dsti, counts, E_);
    k_scan1<<<nb, 256, 0, stream>>>(counts, bsums, N_);
    k_scan2<<<1, 64, 0, stream>>>(bsums, nb);
    k_scan3<<<nb, 256, 0, stream>>>(counts, bsums, rowstart, N_, E_);
    k_binit<<<(NBK + 255) / 256, 256, 0, stream>>>(rowstart, bcursor, NBK);
    k_part <<<(E_ + 255) / 256, 256, 0, stream>>>(srci, dsti, bcursor, tmp, E_);
    hipMemcpyAsync(counts, rowstart, (size_t)N_ * sizeof(int),
                   hipMemcpyDeviceToDevice, stream);          // counts := cursor
    k_fill2<<<(E_ + 255) / 256, 256, 0, stream>>>(tmp, counts, col, E_);

    // ---- layer 1
    k_linear<<<(N_ + 63) / 64, 256, 0, stream>>>(x, W1, b1, A, N_);
    k_gather<true><<<(N_ + 3) / 4, 256, 0, stream>>>(A, rowstart, col,
                                                     g1, be1, m1, v1, B, N_);

    // ---- layer 2
    k_linear<<<(N_ + 63) / 64, 256, 0, stream>>>(B, W2, b2, A, N_);
    k_gather<true><<<(N_ + 3) / 4, 256, 0, stream>>>(A, rowstart, col,
                                                     g2, be2, m2, v2, B, N_);

    // ---- MLP head
    k_final<<<(N_ + 31) / 32, 256, 0, stream>>>(B, Wc1, bc1, Wc2, bc2,
                                                (float*)d_out, N_);
}

// Round 4
// 630.425 us; speedup vs baseline: 1.4262x; 1.4262x over previous
//
#include <hip/hip_runtime.h>
#include <hip/hip_bf16.h>

#define EPS 1e-5f

// ---------------------------------------------------------------- zero ints
__global__ __launch_bounds__(256) void k_zero(int* p, int n) {
    int i = blockIdx.x * 256 + threadIdx.x;
    if (i < n) p[i] = 0;
}

// ---------------------------------------------------------------- histogram + rank
// rank[e] = arrival order of edge e within its dst. One atomic pass; rank is
// written LINEARLY (streaming). This removes atomics from the fill pass.
__global__ __launch_bounds__(256) void k_histrank(const int* __restrict__ dst,
                                                  int* __restrict__ counts,
                                                  int* __restrict__ rank, int nE) {
    int i = blockIdx.x * 256 + threadIdx.x;
    if (i < nE) rank[i] = atomicAdd(&counts[dst[i]], 1);
}

// ---------------------------------------------------------------- scan (3 phases)
__global__ __launch_bounds__(256) void k_scan1(const int* __restrict__ counts,
                                               int* __restrict__ bsums, int n) {
    __shared__ int sdata[256];
    int base = blockIdx.x * 2048;
    int t = threadIdx.x;
    int s = 0;
#pragma unroll
    for (int i = 0; i < 8; ++i) {
        int idx = base + t * 8 + i;
        if (idx < n) s += counts[idx];
    }
    sdata[t] = s;
    __syncthreads();
    for (int off = 128; off > 0; off >>= 1) {
        if (t < off) sdata[t] += sdata[t + off];
        __syncthreads();
    }
    if (t == 0) bsums[blockIdx.x] = sdata[0];
}

__global__ __launch_bounds__(64) void k_scan2(int* __restrict__ bsums, int nb) {
    if (threadIdx.x == 0 && blockIdx.x == 0) {
        int acc = 0;
        for (int i = 0; i < nb; ++i) { int v = bsums[i]; bsums[i] = acc; acc += v; }
    }
}

__global__ __launch_bounds__(256) void k_scan3(const int* __restrict__ counts,
                                               const int* __restrict__ bsums,
                                               int* __restrict__ rowstart,
                                               int n, int nE) {
    __shared__ int sth[256];
    int base = blockIdx.x * 2048;
    int t = threadIdx.x;
    int loc[8];
    int s = 0;
#pragma unroll
    for (int i = 0; i < 8; ++i) {
        int idx = base + t * 8 + i;
        loc[i] = s;
        s += (idx < n) ? counts[idx] : 0;
    }
    sth[t] = s;
    __syncthreads();
    for (int off = 1; off < 256; off <<= 1) {
        int tmp = (t >= off) ? sth[t - off] : 0;
        __syncthreads();
        sth[t] += tmp;
        __syncthreads();
    }
    int excl = sth[t] - s + bsums[blockIdx.x];
#pragma unroll
    for (int i = 0; i < 8; ++i) {
        int idx = base + t * 8 + i;
        if (idx < n) rowstart[idx] = excl + loc[i];
    }
    if (blockIdx.x == 0 && t == 0) rowstart[n] = nE;
}

// ---------------------------------------------------------------- CSR fill (no atomics)
__global__ __launch_bounds__(256) void k_fill3(const int* __restrict__ srci,
                                               const int* __restrict__ dsti,
                                               const int* __restrict__ rank,
                                               const int* __restrict__ rowstart,
                                               int* __restrict__ col, int nE) {
    int e = blockIdx.x * 256 + threadIdx.x;
    if (e < nE) {
        col[rowstart[dsti[e]] + rank[e]] = srci[e];
    }
}

// ---------------------------------------------------------------- linear
__global__ __launch_bounds__(256) void k_linear(const float* __restrict__ X,
                                                const float* __restrict__ W,
                                                const float* __restrict__ bias,
                                                float* __restrict__ out,
                                                int nRows) {
    __shared__ float xs[64][132];
    int row0 = blockIdx.x * 64;
    int tid = threadIdx.x;
    for (int i = tid; i < 64 * 32; i += 256) {
        int r = i >> 5, c4 = (i & 31) << 2;
        float4 v = make_float4(0.f, 0.f, 0.f, 0.f);
        int row = row0 + r;
        if (row < nRows) v = *(const float4*)(X + (size_t)row * 128 + c4);
        *(float4*)&xs[r][c4] = v;
    }
    __syncthreads();

    int cg = tid & 15, rg = tid >> 4;
    int c0 = cg * 8, r0 = rg * 4;
    float acc[4][8];
    float4 b0 = *(const float4*)(bias + c0);
    float4 b1 = *(const float4*)(bias + c0 + 4);
#pragma unroll
    for (int r = 0; r < 4; ++r) {
        acc[r][0] = b0.x; acc[r][1] = b0.y; acc[r][2] = b0.z; acc[r][3] = b0.w;
        acc[r][4] = b1.x; acc[r][5] = b1.y; acc[r][6] = b1.z; acc[r][7] = b1.w;
    }

    for (int k0 = 0; k0 < 128; k0 += 4) {
        float4 xv[4];
#pragma unroll
        for (int r = 0; r < 4; ++r) xv[r] = *(const float4*)&xs[r0 + r][k0];
#pragma unroll
        for (int kk = 0; kk < 4; ++kk) {
            int k = k0 + kk;
            float4 w0 = *(const float4*)(W + k * 128 + c0);
            float4 w1 = *(const float4*)(W + k * 128 + c0 + 4);
            float wv[8] = {w0.x, w0.y, w0.z, w0.w, w1.x, w1.y, w1.z, w1.w};
#pragma unroll
            for (int r = 0; r < 4; ++r) {
                float xk = (&xv[r].x)[kk];
#pragma unroll
                for (int j = 0; j < 8; ++j) acc[r][j] = fmaf(xk, wv[j], acc[r][j]);
            }
        }
    }

#pragma unroll
    for (int r = 0; r < 4; ++r) {
        int row = row0 + r0 + r;
        if (row >= nRows) continue;
        *(float4*)(out + (size_t)row * 128 + c0) =
            make_float4(acc[r][0], acc[r][1], acc[r][2], acc[r][3]);
        *(float4*)(out + (size_t)row * 128 + c0 + 4) =
            make_float4(acc[r][4], acc[r][5], acc[r][6], acc[r][7]);
    }
}

// ---------------------------------------------------------------- gather
template <bool FUSE_BN>
__global__ __launch_bounds__(256) void k_gather(const float* __restrict__ src,
                                                const int* __restrict__ rowstart,
                                                const int* __restrict__ col,
                                                const float* __restrict__ g,
                                                const float* __restrict__ be,
                                                const float* __restrict__ m,
                                                const float* __restrict__ v,
                                                float* __restrict__ out, int nRows) {
    int r = blockIdx.x * 4 + (threadIdx.x >> 6);
    if (r >= nRows) return;
    int lane = threadIdx.x & 63;
    int d0 = lane * 2;
    int s = rowstart[r], e = rowstart[r + 1];

    float2 acc = *(const float2*)(src + (size_t)r * 128 + d0);   // self loop
    int j = s;
    for (; j + 8 <= e; j += 8) {
        int ci[8];
#pragma unroll
        for (int u = 0; u < 8; ++u) ci[u] = col[j + u];
        float2 t[8];
#pragma unroll
        for (int u = 0; u < 8; ++u)
            t[u] = *(const float2*)(src + (size_t)ci[u] * 128 + d0);
#pragma unroll
        for (int u = 0; u < 8; ++u) { acc.x += t[u].x; acc.y += t[u].y; }
    }
    for (; j < e; ++j) {
        int ci = col[j];
        float2 a = *(const float2*)(src + (size_t)ci * 128 + d0);
        acc.x += a.x;
        acc.y += a.y;
    }
    float rc = 1.0f / (float)(e - s + 1);
    float2 o;
    if (FUSE_BN) {
        float2 gv = *(const float2*)(g + d0);
        float2 bev = *(const float2*)(be + d0);
        float2 mv = *(const float2*)(m + d0);
        float2 vv = *(const float2*)(v + d0);
        o.x = fmaxf((acc.x * rc - mv.x) * rsqrtf(vv.x + EPS) * gv.x + bev.x, 0.f);
        o.y = fmaxf((acc.y * rc - mv.y) * rsqrtf(vv.y + EPS) * gv.y + bev.y, 0.f);
    } else {
        o.x = acc.x * rc;
        o.y = acc.y * rc;
    }
    *(float2*)(out + (size_t)r * 128 + d0) = o;
}

// ---------------------------------------------------------------- final head
__global__ __launch_bounds__(256) void k_final(const float* __restrict__ xin,
                                               const float* __restrict__ Wc1,
                                               const float* __restrict__ bc1,
                                               const float* __restrict__ Wc2,
                                               const float* __restrict__ bc2,
                                               float* __restrict__ out, int nRows) {
    __shared__ float xs[32][132];
    __shared__ float w1s[128][64];
    __shared__ float hs[32][68];
    int row0 = blockIdx.x * 32;
    int tid = threadIdx.x;

    for (int i = tid; i < 2048; i += 256) {
        int kk = i >> 4, c4 = (i & 15) << 2;
        *(float4*)&w1s[kk][c4] = *(const float4*)(Wc1 + kk * 64 + c4);
    }
    for (int i = tid; i < 1024; i += 256) {
        int r = i >> 5, c4 = (i & 31) << 2;
        int row = row0 + r;
        float4 o = make_float4(0.f, 0.f, 0.f, 0.f);
        if (row < nRows) o = *(const float4*)(xin + (size_t)row * 128 + c4);
        *(float4*)&xs[r][c4] = o;
    }
    __syncthreads();

    int cg = tid & 15, rg = tid >> 4;
    int c0 = cg * 4, r0 = rg * 2;
    float acc[2][4];
    float4 bc = *(const float4*)(bc1 + c0);
    acc[0][0] = bc.x; acc[0][1] = bc.y; acc[0][2] = bc.z; acc[0][3] = bc.w;
    acc[1][0] = bc.x; acc[1][1] = bc.y; acc[1][2] = bc.z; acc[1][3] = bc.w;
    for (int k = 0; k < 128; ++k) {
        float4 w4 = *(const float4*)&w1s[k][c0];
        float x0 = xs[r0][k], x1 = xs[r0 + 1][k];
        acc[0][0] = fmaf(x0, w4.x, acc[0][0]);
        acc[0][1] = fmaf(x0, w4.y, acc[0][1]);
        acc[0][2] = fmaf(x0, w4.z, acc[0][2]);
        acc[0][3] = fmaf(x0, w4.w, acc[0][3]);
        acc[1][0] = fmaf(x1, w4.x, acc[1][0]);
        acc[1][1] = fmaf(x1, w4.y, acc[1][1]);
        acc[1][2] = fmaf(x1, w4.z, acc[1][2]);
        acc[1][3] = fmaf(x1, w4.w, acc[1][3]);
    }
    *(float4*)&hs[r0][c0] = make_float4(fmaxf(acc[0][0], 0.f), fmaxf(acc[0][1], 0.f),
                                        fmaxf(acc[0][2], 0.f), fmaxf(acc[0][3], 0.f));
    *(float4*)&hs[r0 + 1][c0] = make_float4(fmaxf(acc[1][0], 0.f), fmaxf(acc[1][1], 0.f),
                                            fmaxf(acc[1][2], 0.f), fmaxf(acc[1][3], 0.f));
    __syncthreads();

    if (tid < 64) {
        int r = tid >> 1, oc = tid & 1;
        float s = bc2[oc];
        for (int c = 0; c < 64; ++c) s = fmaf(hs[r][c], Wc2[c * 2 + oc], s);
        int row = row0 + r;
        if (row < nRows) out[(size_t)row * 2 + oc] = s;
    }
}

// ---------------------------------------------------------------- launch
extern "C" void kernel_launch(void* const* d_in, const int* in_sizes, int n_in,
                              void* d_out, int out_size, void* d_ws, size_t ws_size,
                              hipStream_t stream) {
    const float* x   = (const float*)d_in[0];
    const int*   ei  = (const int*)d_in[1];
    const float* W1  = (const float*)d_in[2];
    const float* b1  = (const float*)d_in[3];
    const float* g1  = (const float*)d_in[4];
    const float* be1 = (const float*)d_in[5];
    const float* m1  = (const float*)d_in[6];
    const float* v1  = (const float*)d_in[7];
    const float* W2  = (const float*)d_in[8];
    const float* b2  = (const float*)d_in[9];
    const float* g2  = (const float*)d_in[10];
    const float* be2 = (const float*)d_in[11];
    const float* m2  = (const float*)d_in[12];
    const float* v2  = (const float*)d_in[13];
    const float* Wc1 = (const float*)d_in[14];
    const float* bc1 = (const float*)d_in[15];
    const float* Wc2 = (const float*)d_in[16];
    const float* bc2 = (const float*)d_in[17];

    const int N_ = in_sizes[0] / 128;
    const int E_ = in_sizes[1] / 2;
    const int* srci = ei;
    const int* dsti = ei + E_;

    float* A = (float*)d_ws;                       // [N,128]
    float* B = A + (size_t)N_ * 128;               // [N,128]; rank aliases B
    int* rank = (int*)B;                           // [E] int, dead before gather1
    int* counts   = (int*)(B + (size_t)N_ * 128);  // N
    int* rowstart = counts + N_;                   // N+1
    int* bsums    = rowstart + N_ + 1;             // 256
    int* col      = bsums + 256;                   // E

    const int nb = (N_ + 2047) / 2048;

    // ---- CSR build (rank trick: single atomic pass, atomic-free fill)
    k_zero    <<<(N_ + 255) / 256, 256, 0, stream>>>(counts, N_);
    k_histrank<<<(E_ + 255) / 256, 256, 0, stream>>>(dsti, counts, rank, E_);
    k_scan1   <<<nb, 256, 0, stream>>>(counts, bsums, N_);
    k_scan2   <<<1, 64, 0, stream>>>(bsums, nb);
    k_scan3   <<<nb, 256, 0, stream>>>(counts, bsums, rowstart, N_, E_);
    k_fill3   <<<(E_ + 255) / 256, 256, 0, stream>>>(srci, dsti, rank, rowstart,
                                                     col, E_);

    // ---- layer 1
    k_linear<<<(N_ + 63) / 64, 256, 0, stream>>>(x, W1, b1, A, N_);
    k_gather<true><<<(N_ + 3) / 4, 256, 0, stream>>>(A, rowstart, col,
                                                     g1, be1, m1, v1, B, N_);

    // ---- layer 2
    k_linear<<<(N_ + 63) / 64, 256, 0, stream>>>(B, W2, b2, A, N_);
    k_gather<true><<<(N_ + 3) / 4, 256, 0, stream>>>(A, rowstart, col,
                                                     g2, be2, m2, v2, B, N_);

    // ---- MLP head
    k_final<<<(N_ + 31) / 32, 256, 0, stream>>>(B, Wc1, bc1, Wc2, bc2,
                                                (float*)d_out, N_);
}